// Round 1
// baseline (10715.243 us; speedup 1.0000x reference)
//
#include <hip/hip_runtime.h>
#include <cmath>

#define HH 512
#define WW 512
#define NB 8
#define CIN 4
#define C2 32
#define C3 16
#define CF 8
#define HW (HH*WW)      /* 262144 */
#define NPIX (NB*HW)    /* 2097152 */

__device__ __forceinline__ float lrelu_f(float v){ return v < 0.f ? 0.2f*v : v; }
__device__ __forceinline__ int reflect_i(int i){ int r = i < 0 ? -i : i; return r >= HH ? 2*HH - 2 - r : r; }

// ---------------------------------------------------------------------------
// Conv 3x3 (zero pad=1, cross-correlation, OIHW weights). Thread = 4 adjacent
// pixels x 8 output channels. Weights in LDS (uniform -> broadcast reads).
// ---------------------------------------------------------------------------
template<int Ci, int Co, bool LRELU>
__global__ __launch_bounds__(256) void k_conv(const float* __restrict__ in,
                                              const float* __restrict__ wgt,
                                              const float* __restrict__ bias,
                                              float* __restrict__ outp)
{
    constexpr int NG = Co/8;
    __shared__ float wl[Co*Ci*9];
    __shared__ float bl[Co];
    for (int i = threadIdx.x; i < Co*Ci*9; i += 256) wl[i] = wgt[i];
    if (threadIdx.x < Co) bl[threadIdx.x] = bias[threadIdx.x];
    __syncthreads();

    int t   = blockIdx.x*256 + threadIdx.x;
    int pix = t & 65535;
    int r   = t >> 16;
    int cg  = r % NG;
    int b   = r / NG;
    int h   = pix >> 7;
    int w0  = (pix & 127) << 2;
    int co0 = cg*8;
    const float* inb = in + (size_t)b*Ci*HW;

    float acc[8][4];
    #pragma unroll
    for (int j=0;j<8;j++){
        float bv = bl[co0+j];
        #pragma unroll
        for (int p=0;p<4;p++) acc[j][p] = bv;
    }

    #pragma unroll 1
    for (int ci=0; ci<Ci; ci++){
        float v[3][6];
        const float* inc = inb + (size_t)ci*HW;
        #pragma unroll
        for (int dy=0;dy<3;dy++){
            int hh = h + dy - 1;
            int hc = hh < 0 ? 0 : (hh > HH-1 ? HH-1 : hh);
            bool hok = (unsigned)hh < (unsigned)HH;
            #pragma unroll
            for (int dx=0;dx<6;dx++){
                int wx = w0 + dx - 1;
                int wc = wx < 0 ? 0 : (wx > WW-1 ? WW-1 : wx);
                float val = inc[hc*WW + wc];
                v[dy][dx] = (hok && (unsigned)wx < (unsigned)WW) ? val : 0.f;
            }
        }
        #pragma unroll
        for (int j=0;j<8;j++){
            const float* wr = &wl[((co0+j)*Ci + ci)*9];
            #pragma unroll
            for (int dy=0;dy<3;dy++){
                #pragma unroll
                for (int dx=0;dx<3;dx++){
                    float wv = wr[dy*3+dx];
                    #pragma unroll
                    for (int p=0;p<4;p++)
                        acc[j][p] = fmaf(v[dy][dx+p], wv, acc[j][p]);
                }
            }
        }
    }

    float* ob = outp + (size_t)b*Co*HW;
    #pragma unroll
    for (int j=0;j<8;j++){
        float4 o;
        o.x = LRELU ? lrelu_f(acc[j][0]) : acc[j][0];
        o.y = LRELU ? lrelu_f(acc[j][1]) : acc[j][1];
        o.z = LRELU ? lrelu_f(acc[j][2]) : acc[j][2];
        o.w = LRELU ? lrelu_f(acc[j][3]) : acc[j][3];
        *(float4*)(ob + (size_t)(co0+j)*HW + h*WW + w0) = o;
    }
}

// ---------------------------------------------------------------------------
// Horizontal box pass with reflect padding. Block = (b, row). Stages all 8
// channel rows (value + square) into LDS, writes channel-last [b][row][col][c]
// sums so the V-pass can do float4 loads.
// ---------------------------------------------------------------------------
template<int WS>
__global__ __launch_bounds__(256) void k_hpass(const float* __restrict__ f,
                                               float* __restrict__ hm,
                                               float* __restrict__ hm2,
                                               int rs_p, int rows_p)
{
    constexpr int P = WS/2;
    constexpr int L = WW + 2*P;
    __shared__ float sv[CF][L];
    __shared__ float sq[CF][L];

    int bid  = blockIdx.x;
    int roff = bid % rows_p;
    int b    = bid / rows_p;
    int rabs = rs_p + roff;

    for (int i = threadIdx.x; i < CF*L; i += 256){
        int c = i / L, j = i % L;
        int s = j - P;
        s = s < 0 ? -s : (s > HH-1 ? 2*HH-2 - s : s);
        float v = f[(((size_t)b*CF + c)*HH + rabs)*WW + s];
        sv[c][j] = v; sq[c][j] = v*v;
    }
    __syncthreads();

    size_t rowbase = ((size_t)b*rows_p + roff)*WW;
    #pragma unroll
    for (int half = 0; half < 2; half++){
        int col = threadIdx.x + half*256;
        float os[CF], oq[CF];
        #pragma unroll
        for (int c=0;c<CF;c++){
            float s0=0.f, q0=0.f;
            #pragma unroll
            for (int k=0;k<WS;k++){ s0 += sv[c][col+k]; q0 += sq[c][col+k]; }
            os[c]=s0; oq[c]=q0;
        }
        float* dst  = hm  + (rowbase + col)*CF;
        float* dst2 = hm2 + (rowbase + col)*CF;
        ((float4*)dst )[0] = make_float4(os[0],os[1],os[2],os[3]);
        ((float4*)dst )[1] = make_float4(os[4],os[5],os[6],os[7]);
        ((float4*)dst2)[0] = make_float4(oq[0],oq[1],oq[2],oq[3]);
        ((float4*)dst2)[1] = make_float4(oq[4],oq[5],oq[6],oq[7]);
    }
}

#define ADDLO(s,v) { s[0]+=(v).x; s[1]+=(v).y; s[2]+=(v).z; s[3]+=(v).w; }
#define ADDHI(s,v) { s[4]+=(v).x; s[5]+=(v).y; s[6]+=(v).z; s[7]+=(v).w; }
#define SUBLO(s,v) { s[0]-=(v).x; s[1]-=(v).y; s[2]-=(v).z; s[3]-=(v).w; }
#define SUBHI(s,v) { s[4]-=(v).x; s[5]-=(v).y; s[6]-=(v).z; s[7]-=(v).w; }

// ---------------------------------------------------------------------------
// Vertical box pass + var/sqrt/channel-sum/pow0.8 + fused accumulation.
// Thread = (b, col, 16-row chunk) with running column sums over 8 channels.
// ---------------------------------------------------------------------------
template<int WS>
__global__ __launch_bounds__(256) void k_vpass(const float* __restrict__ hm,
                                               const float* __restrict__ hm2,
                                               float* __restrict__ fused,
                                               const float* __restrict__ fwv, int sidx,
                                               int r0, int r1, int rs_p, int rows_p, int nch)
{
    constexpr int P = WS/2;
    constexpr float inv = 1.f/(float)(WS*WS);
    int t    = blockIdx.x*256 + threadIdx.x;
    int col  = t & (WW-1);
    int rr   = t >> 9;
    int chunk= rr % nch;
    int b    = rr / nch;
    int h0   = r0 + chunk*16;
    int hend = min(r1, h0+16);
    if (h0 >= hend || b >= NB) return;

    float s[CF], q[CF];
    #pragma unroll
    for (int c=0;c<CF;c++){ s[c]=0.f; q[c]=0.f; }

    for (int dy=-P; dy<=P; dy++){
        int rI = reflect_i(h0+dy);
        size_t base = (((size_t)b*rows_p + (rI - rs_p))*WW + col)*CF;
        float4 a0 = *(const float4*)(hm +base);
        float4 a1 = *(const float4*)(hm +base+4);
        float4 c0 = *(const float4*)(hm2+base);
        float4 c1 = *(const float4*)(hm2+base+4);
        ADDLO(s,a0); ADDHI(s,a1); ADDLO(q,c0); ADDHI(q,c1);
    }

    float fw = fwv[sidx];
    for (int h=h0; h<hend; h++){
        float acc = 0.f;
        #pragma unroll
        for (int c=0;c<CF;c++){
            float m  = s[c]*inv;
            float m2 = q[c]*inv;
            float var = fmaf(-m, m, m2);
            var = fmaxf(var, 1e-6f);
            acc += sqrtf(var);
        }
        float res = acc * 0.125f;
        float val = powf(res, 0.8f);
        size_t oi = ((size_t)b*HH + h)*WW + col;
        fused[oi] += fw * val;
        if (h+1 < hend){
            int ro = reflect_i(h - P);
            int ri = reflect_i(h + 1 + P);
            size_t bo = (((size_t)b*rows_p + (ro-rs_p))*WW + col)*CF;
            size_t bi = (((size_t)b*rows_p + (ri-rs_p))*WW + col)*CF;
            float4 a0 = *(const float4*)(hm +bi);
            float4 a1 = *(const float4*)(hm +bi+4);
            float4 c0 = *(const float4*)(hm2+bi);
            float4 c1 = *(const float4*)(hm2+bi+4);
            ADDLO(s,a0); ADDHI(s,a1); ADDLO(q,c0); ADDHI(q,c1);
            a0 = *(const float4*)(hm +bo);
            a1 = *(const float4*)(hm +bo+4);
            c0 = *(const float4*)(hm2+bo);
            c1 = *(const float4*)(hm2+bo+4);
            SUBLO(s,a0); SUBHI(s,a1); SUBLO(q,c0); SUBHI(q,c1);
        }
    }
}

// ---------------------------------------------------------------------------
// Exact quantile machinery: two-level 16-bit radix histograms (values >= 0,
// so float bit pattern is order-preserving).
// ---------------------------------------------------------------------------
__global__ void k_hist_hi(const float* __restrict__ fused, const float* __restrict__ fb,
                          unsigned* __restrict__ hist)
{
    float fbv = fb[0];
    int i = blockIdx.x*256 + threadIdx.x;
    int stride = gridDim.x*256;
    for (; i < NPIX; i += stride){
        float v = fmaxf(fused[i] + fbv, 0.f);
        unsigned u = __float_as_uint(v);
        atomicAdd(&hist[u >> 16], 1u);
    }
}

__global__ void k_scan_hi(const unsigned* __restrict__ hist, int* __restrict__ tbin, int* __restrict__ trank)
{
    __shared__ unsigned csum[256];
    __shared__ unsigned cbase[256];
    int t = threadIdx.x;
    unsigned s = 0;
    for (int i=0;i<256;i++) s += hist[t*256+i];
    csum[t] = s;
    __syncthreads();
    if (t == 0){ unsigned run=0; for (int i=0;i<256;i++){ cbase[i]=run; run += csum[i]; } }
    __syncthreads();
    const unsigned RK[4] = {524287u, 524288u, 1572863u, 1572864u};
    unsigned cum = cbase[t];
    for (int i=0;i<256;i++){
        unsigned cnt = hist[t*256+i];
        if (cnt){
            #pragma unroll
            for (int qi=0;qi<4;qi++){
                unsigned k = RK[qi];
                if (k >= cum && k < cum+cnt){ tbin[qi] = t*256+i; trank[qi] = (int)(k - cum); }
            }
        }
        cum += cnt;
    }
}

__global__ void k_hist_lo(const float* __restrict__ fused, const float* __restrict__ fb,
                          const int* __restrict__ tbin, unsigned* __restrict__ histlo)
{
    float fbv = fb[0];
    int t0=tbin[0], t1=tbin[1], t2=tbin[2], t3=tbin[3];
    int i = blockIdx.x*256 + threadIdx.x;
    int stride = gridDim.x*256;
    for (; i < NPIX; i += stride){
        float v = fmaxf(fused[i] + fbv, 0.f);
        unsigned u = __float_as_uint(v);
        int hi = (int)(u >> 16);
        unsigned lo = u & 0xffffu;
        if (hi==t0) atomicAdd(&histlo[lo], 1u);
        if (hi==t1) atomicAdd(&histlo[65536u+lo], 1u);
        if (hi==t2) atomicAdd(&histlo[131072u+lo], 1u);
        if (hi==t3) atomicAdd(&histlo[196608u+lo], 1u);
    }
}

__global__ void k_scan_lo(const unsigned* __restrict__ histlo, const int* __restrict__ tbin,
                          const int* __restrict__ trank, float* __restrict__ ostat)
{
    int qi = blockIdx.x;
    const unsigned* hist = histlo + (size_t)qi*65536;
    __shared__ unsigned csum[256];
    __shared__ unsigned cbase[256];
    int t = threadIdx.x;
    unsigned s = 0;
    for (int i=0;i<256;i++) s += hist[t*256+i];
    csum[t] = s;
    __syncthreads();
    if (t == 0){ unsigned run=0; for (int i=0;i<256;i++){ cbase[i]=run; run += csum[i]; } }
    __syncthreads();
    unsigned k = (unsigned)trank[qi];
    unsigned cum = cbase[t];
    for (int i=0;i<256;i++){
        unsigned cnt = hist[t*256+i];
        if (cnt && k >= cum && k < cum+cnt)
            ostat[qi] = __uint_as_float(((unsigned)tbin[qi] << 16) | (unsigned)(t*256+i));
        cum += cnt;
    }
}

// ---------------------------------------------------------------------------
// Global per-(b,c) std of x, ddof=1, via double partial sums (deterministic).
// ---------------------------------------------------------------------------
__global__ void k_gstd_part(const float* __restrict__ x, double* __restrict__ part)
{
    int bid = blockIdx.x;
    int plane = bid >> 3, chunk = bid & 7;
    const float4* p4 = (const float4*)(x + (size_t)plane*HW + (size_t)chunk*32768);
    int t = threadIdx.x;
    double s=0.0, s2=0.0;
    for (int k=0;k<32;k++){
        float4 v = p4[k*256 + t];
        s  += (double)v.x + (double)v.y + (double)v.z + (double)v.w;
        s2 += (double)v.x*v.x + (double)v.y*v.y + (double)v.z*v.z + (double)v.w*v.w;
    }
    __shared__ double rs[256], rq[256];
    rs[t]=s; rq[t]=s2; __syncthreads();
    for (int off=128; off>0; off>>=1){
        if (t<off){ rs[t]+=rs[t+off]; rq[t]+=rq[t+off]; }
        __syncthreads();
    }
    if (t==0){ part[bid*2]=rs[0]; part[bid*2+1]=rq[0]; }
}

__global__ void k_gstd_final(const double* __restrict__ part, float* __restrict__ gstd)
{
    int t = threadIdx.x;
    if (t < 32){
        double s=0.0, s2=0.0;
        for (int j=0;j<8;j++){ s += part[(t*8+j)*2]; s2 += part[(t*8+j)*2+1]; }
        const double N = 262144.0;
        double var = (s2 - s*s/N) / (N - 1.0);
        gstd[t] = (float)sqrt(var < 0.0 ? 0.0 : var);
    }
}

__global__ void k_finalize(const float* __restrict__ ostat, const float* __restrict__ gstd,
                           const float* __restrict__ cwin, float* __restrict__ lov, float* __restrict__ hiv)
{
    int t = threadIdx.x;
    if (t < 32){
        float q25 = ostat[0] + 0.75f*(ostat[1]-ostat[0]);
        float q75 = ostat[2] + 0.25f*(ostat[3]-ostat[2]);
        float iqr = q75 - q25;
        float lo_b = q25 - 0.5f*iqr, hi_b = q75 + 0.5f*iqr;
        int c = t & 3;
        float m = fmaxf(fmaxf(cwin[0],cwin[1]), fmaxf(cwin[2],cwin[3]));
        float e0 = expf(cwin[0]-m), e1 = expf(cwin[1]-m), e2 = expf(cwin[2]-m), e3 = expf(cwin[3]-m);
        float smc = expf(cwin[c]-m) / (e0+e1+e2+e3);
        float g  = gstd[t];
        float gf = fminf(fmaxf(g*5.f, 0.5f), 2.f);
        float cf = fminf(fmaxf(smc*g*2.f, 0.8f), 1.2f);
        lov[t] = lo_b*gf*cf;
        hiv[t] = hi_b*gf*cf;
    }
}

__global__ void k_mask(const float* __restrict__ fused_in, const float* __restrict__ fb,
                       const float* __restrict__ lov, const float* __restrict__ hiv,
                       float* __restrict__ outp)
{
    int i = blockIdx.x*256 + threadIdx.x;
    float F = fmaxf(fused_in[i] + fb[0], 0.f);
    int b = i >> 18;
    float o = 0.f;
    #pragma unroll
    for (int c=0;c<4;c++){
        float lo = lov[b*4+c], hi = hiv[b*4+c];
        float n = (F - lo) / (hi - lo);
        n = fminf(fmaxf(n, 0.f), 1.f);
        o += 1.f/(1.f + expf(3.f - 6.f*n));
    }
    outp[i] = 0.25f * o;
}

// ---------------------------------------------------------------------------
extern "C" void kernel_launch(void* const* d_in, const int* in_sizes, int n_in,
                              void* d_out, int out_size, void* d_ws, size_t ws_size,
                              hipStream_t stream)
{
    const float* x  = (const float*)d_in[0];
    const float* w1 = (const float*)d_in[1];
    const float* b1 = (const float*)d_in[2];
    const float* w2 = (const float*)d_in[3];
    const float* b2 = (const float*)d_in[4];
    const float* w3 = (const float*)d_in[5];
    const float* b3 = (const float*)d_in[6];
    const float* fw = (const float*)d_in[7];
    const float* fb = (const float*)d_in[8];
    const float* cw = (const float*)d_in[9];
    float* out = (float*)d_out;
    char* ws = (char*)d_ws;

    size_t off = 0;
    auto take = [&](size_t bytes)->size_t{ size_t o = off; off += (bytes + 255) & ~(size_t)255; return o; };
    size_t o_f      = take((size_t)NB*CF*HW*4);
    size_t o_hist   = take((size_t)65536*4);
    size_t o_histlo = take((size_t)4*65536*4);
    size_t o_tb     = take(4*4);
    size_t o_tr     = take(4*4);
    size_t o_os     = take(4*4);
    size_t o_part   = take(512*8);
    size_t o_gs     = take(32*4);
    size_t o_lo     = take(32*4);
    size_t o_hi     = take(32*4);
    size_t fixed_end = off;

    size_t szA_pb = (size_t)C2*HW*4, szB_pb = (size_t)C3*HW*4;
    auto hmbytes = [&](int band)->size_t{ return (size_t)NB*(band+48)*WW*CF*4; };
    bool fullconv = false;
    int band = 16;
    if (ws_size >= fixed_end + szA_pb*NB + szB_pb*NB + 2*hmbytes(512) + 4096){
        fullconv = true; band = 512;
    } else {
        const int cand[6] = {512,256,128,64,32,16};
        for (int i=0;i<6;i++){
            if (ws_size >= fixed_end + szA_pb + szB_pb + 2*hmbytes(cand[i]) + 4096){ band = cand[i]; break; }
        }
    }
    size_t o_A   = take(fullconv ? szA_pb*NB : szA_pb);
    size_t o_B   = take(fullconv ? szB_pb*NB : szB_pb);
    size_t o_hm  = take(hmbytes(band));
    size_t o_hm2 = take(hmbytes(band));

    float*    fbuf   = (float*)(ws + o_f);
    float*    f1     = (float*)(ws + o_A);
    float*    f2     = (float*)(ws + o_B);
    float*    hm     = (float*)(ws + o_hm);
    float*    hm2    = (float*)(ws + o_hm2);
    unsigned* hist   = (unsigned*)(ws + o_hist);
    unsigned* histlo = (unsigned*)(ws + o_histlo);
    int*      tb     = (int*)(ws + o_tb);
    int*      tr     = (int*)(ws + o_tr);
    float*    osv    = (float*)(ws + o_os);
    double*   part   = (double*)(ws + o_part);
    float*    gs     = (float*)(ws + o_gs);
    float*    lov    = (float*)(ws + o_lo);
    float*    hiv    = (float*)(ws + o_hi);

    // --- conv stack ---
    if (fullconv){
        k_conv<CIN,C2,true ><<<NB*1024,256,0,stream>>>(x,  w1, b1, f1);
        k_conv<C2, C3,true ><<<NB*512, 256,0,stream>>>(f1, w2, b2, f2);
        k_conv<C3, CF,false><<<NB*256, 256,0,stream>>>(f2, w3, b3, fbuf);
    } else {
        for (int b=0;b<NB;b++){
            k_conv<CIN,C2,true ><<<1024,256,0,stream>>>(x + (size_t)b*CIN*HW, w1, b1, f1);
            k_conv<C2, C3,true ><<<512, 256,0,stream>>>(f1, w2, b2, f2);
            k_conv<C3, CF,false><<<256, 256,0,stream>>>(f2, w3, b3, fbuf + (size_t)b*CF*HW);
        }
    }

    // --- global stds (independent of conv chain) ---
    k_gstd_part<<<256,256,0,stream>>>(x, part);
    k_gstd_final<<<1,256,0,stream>>>(part, gs);

    // --- multi-scale std maps, accumulated into d_out as fused sum ---
    hipMemsetAsync(out, 0, (size_t)NPIX*4, stream);
    for (int s=0;s<3;s++){
        int wsz = (s==0) ? 11 : (s==1 ? 25 : 49);
        int P = wsz/2;
        for (int r0=0; r0<HH; r0+=band){
            int r1  = (r0+band < HH) ? r0+band : HH;
            int rsp = (r0-P > 0) ? r0-P : 0;
            int rep = (r1+P < HH) ? r1+P : HH;
            int rows_p = rep - rsp;
            int nch = (r1 - r0 + 15)/16;
            if (wsz==11){
                k_hpass<11><<<NB*rows_p,256,0,stream>>>(fbuf, hm, hm2, rsp, rows_p);
                k_vpass<11><<<16*nch,256,0,stream>>>(hm, hm2, out, fw, s, r0, r1, rsp, rows_p, nch);
            } else if (wsz==25){
                k_hpass<25><<<NB*rows_p,256,0,stream>>>(fbuf, hm, hm2, rsp, rows_p);
                k_vpass<25><<<16*nch,256,0,stream>>>(hm, hm2, out, fw, s, r0, r1, rsp, rows_p, nch);
            } else {
                k_hpass<49><<<NB*rows_p,256,0,stream>>>(fbuf, hm, hm2, rsp, rows_p);
                k_vpass<49><<<16*nch,256,0,stream>>>(hm, hm2, out, fw, s, r0, r1, rsp, rows_p, nch);
            }
        }
    }

    // --- exact quantiles (two-level radix histogram selection) ---
    hipMemsetAsync(hist,   0, (size_t)65536*4,   stream);
    hipMemsetAsync(histlo, 0, (size_t)4*65536*4, stream);
    k_hist_hi<<<2048,256,0,stream>>>(out, fb, hist);
    k_scan_hi<<<1,256,0,stream>>>(hist, tb, tr);
    k_hist_lo<<<2048,256,0,stream>>>(out, fb, tb, histlo);
    k_scan_lo<<<4,256,0,stream>>>(histlo, tb, tr, osv);

    // --- thresholds + mask (in-place on d_out) ---
    k_finalize<<<1,64,0,stream>>>(osv, gs, cw, lov, hiv);
    k_mask<<<NPIX/256,256,0,stream>>>(out, fb, lov, hiv, out);
}

// Round 2
// 1482.936 us; speedup vs baseline: 7.2257x; 7.2257x over previous
//
#include <hip/hip_runtime.h>
#include <cmath>

#define HH 512
#define WW 512
#define NB 8
#define CIN 4
#define C2 32
#define C3 16
#define CF 8
#define HW (HH*WW)      /* 262144 */
#define NPIX (NB*HW)    /* 2097152 */

__device__ __forceinline__ float lrelu_f(float v){ return v < 0.f ? 0.2f*v : v; }
__device__ __forceinline__ int reflect_i(int i){ int r = i < 0 ? -i : i; return r >= HH ? 2*HH - 2 - r : r; }

// ---------------------------------------------------------------------------
// Conv 3x3 (zero pad=1, cross-correlation, OIHW weights). Thread = 4 adjacent
// pixels x 8 output channels. Weights in LDS (uniform -> broadcast reads).
// ---------------------------------------------------------------------------
template<int Ci, int Co, bool LRELU>
__global__ __launch_bounds__(256) void k_conv(const float* __restrict__ in,
                                              const float* __restrict__ wgt,
                                              const float* __restrict__ bias,
                                              float* __restrict__ outp)
{
    constexpr int NG = Co/8;
    __shared__ float wl[Co*Ci*9];
    __shared__ float bl[Co];
    for (int i = threadIdx.x; i < Co*Ci*9; i += 256) wl[i] = wgt[i];
    if (threadIdx.x < Co) bl[threadIdx.x] = bias[threadIdx.x];
    __syncthreads();

    int t   = blockIdx.x*256 + threadIdx.x;
    int pix = t & 65535;
    int r   = t >> 16;
    int cg  = r % NG;
    int b   = r / NG;
    int h   = pix >> 7;
    int w0  = (pix & 127) << 2;
    int co0 = cg*8;
    const float* inb = in + (size_t)b*Ci*HW;

    float acc[8][4];
    #pragma unroll
    for (int j=0;j<8;j++){
        float bv = bl[co0+j];
        #pragma unroll
        for (int p=0;p<4;p++) acc[j][p] = bv;
    }

    #pragma unroll 1
    for (int ci=0; ci<Ci; ci++){
        float v[3][6];
        const float* inc = inb + (size_t)ci*HW;
        #pragma unroll
        for (int dy=0;dy<3;dy++){
            int hh = h + dy - 1;
            int hc = hh < 0 ? 0 : (hh > HH-1 ? HH-1 : hh);
            bool hok = (unsigned)hh < (unsigned)HH;
            #pragma unroll
            for (int dx=0;dx<6;dx++){
                int wx = w0 + dx - 1;
                int wc = wx < 0 ? 0 : (wx > WW-1 ? WW-1 : wx);
                float val = inc[hc*WW + wc];
                v[dy][dx] = (hok && (unsigned)wx < (unsigned)WW) ? val : 0.f;
            }
        }
        #pragma unroll
        for (int j=0;j<8;j++){
            const float* wr = &wl[((co0+j)*Ci + ci)*9];
            #pragma unroll
            for (int dy=0;dy<3;dy++){
                #pragma unroll
                for (int dx=0;dx<3;dx++){
                    float wv = wr[dy*3+dx];
                    #pragma unroll
                    for (int p=0;p<4;p++)
                        acc[j][p] = fmaf(v[dy][dx+p], wv, acc[j][p]);
                }
            }
        }
    }

    float* ob = outp + (size_t)b*Co*HW;
    #pragma unroll
    for (int j=0;j<8;j++){
        float4 o;
        o.x = LRELU ? lrelu_f(acc[j][0]) : acc[j][0];
        o.y = LRELU ? lrelu_f(acc[j][1]) : acc[j][1];
        o.z = LRELU ? lrelu_f(acc[j][2]) : acc[j][2];
        o.w = LRELU ? lrelu_f(acc[j][3]) : acc[j][3];
        *(float4*)(ob + (size_t)(co0+j)*HW + h*WW + w0) = o;
    }
}

// ---------------------------------------------------------------------------
// Horizontal box pass with reflect padding. Block = (b, row). Stages all 8
// channel rows (value + square) into LDS, writes channel-last [b][row][col][c]
// sums so the V-pass can do float4 loads.
// ---------------------------------------------------------------------------
template<int WS>
__global__ __launch_bounds__(256) void k_hpass(const float* __restrict__ f,
                                               float* __restrict__ hm,
                                               float* __restrict__ hm2,
                                               int rs_p, int rows_p)
{
    constexpr int P = WS/2;
    constexpr int L = WW + 2*P;
    __shared__ float sv[CF][L];
    __shared__ float sq[CF][L];

    int bid  = blockIdx.x;
    int roff = bid % rows_p;
    int b    = bid / rows_p;
    int rabs = rs_p + roff;

    for (int i = threadIdx.x; i < CF*L; i += 256){
        int c = i / L, j = i % L;
        int s = j - P;
        s = s < 0 ? -s : (s > HH-1 ? 2*HH-2 - s : s);
        float v = f[(((size_t)b*CF + c)*HH + rabs)*WW + s];
        sv[c][j] = v; sq[c][j] = v*v;
    }
    __syncthreads();

    size_t rowbase = ((size_t)b*rows_p + roff)*WW;
    #pragma unroll
    for (int half = 0; half < 2; half++){
        int col = threadIdx.x + half*256;
        float os[CF], oq[CF];
        #pragma unroll
        for (int c=0;c<CF;c++){
            float s0=0.f, q0=0.f;
            #pragma unroll
            for (int k=0;k<WS;k++){ s0 += sv[c][col+k]; q0 += sq[c][col+k]; }
            os[c]=s0; oq[c]=q0;
        }
        float* dst  = hm  + (rowbase + col)*CF;
        float* dst2 = hm2 + (rowbase + col)*CF;
        ((float4*)dst )[0] = make_float4(os[0],os[1],os[2],os[3]);
        ((float4*)dst )[1] = make_float4(os[4],os[5],os[6],os[7]);
        ((float4*)dst2)[0] = make_float4(oq[0],oq[1],oq[2],oq[3]);
        ((float4*)dst2)[1] = make_float4(oq[4],oq[5],oq[6],oq[7]);
    }
}

#define ADDLO(s,v) { s[0]+=(v).x; s[1]+=(v).y; s[2]+=(v).z; s[3]+=(v).w; }
#define ADDHI(s,v) { s[4]+=(v).x; s[5]+=(v).y; s[6]+=(v).z; s[7]+=(v).w; }
#define SUBLO(s,v) { s[0]-=(v).x; s[1]-=(v).y; s[2]-=(v).z; s[3]-=(v).w; }
#define SUBHI(s,v) { s[4]-=(v).x; s[5]-=(v).y; s[6]-=(v).z; s[7]-=(v).w; }

// ---------------------------------------------------------------------------
// Vertical box pass + var/sqrt/channel-sum/pow0.8 + fused accumulation.
// Thread = (b, col, 16-row chunk) with running column sums over 8 channels.
// ---------------------------------------------------------------------------
template<int WS>
__global__ __launch_bounds__(256) void k_vpass(const float* __restrict__ hm,
                                               const float* __restrict__ hm2,
                                               float* __restrict__ fused,
                                               const float* __restrict__ fwv, int sidx,
                                               int r0, int r1, int rs_p, int rows_p, int nch)
{
    constexpr int P = WS/2;
    constexpr float inv = 1.f/(float)(WS*WS);
    int t    = blockIdx.x*256 + threadIdx.x;
    int col  = t & (WW-1);
    int rr   = t >> 9;
    int chunk= rr % nch;
    int b    = rr / nch;
    int h0   = r0 + chunk*16;
    int hend = min(r1, h0+16);
    if (h0 >= hend || b >= NB) return;

    float s[CF], q[CF];
    #pragma unroll
    for (int c=0;c<CF;c++){ s[c]=0.f; q[c]=0.f; }

    for (int dy=-P; dy<=P; dy++){
        int rI = reflect_i(h0+dy);
        size_t base = (((size_t)b*rows_p + (rI - rs_p))*WW + col)*CF;
        float4 a0 = *(const float4*)(hm +base);
        float4 a1 = *(const float4*)(hm +base+4);
        float4 c0 = *(const float4*)(hm2+base);
        float4 c1 = *(const float4*)(hm2+base+4);
        ADDLO(s,a0); ADDHI(s,a1); ADDLO(q,c0); ADDHI(q,c1);
    }

    float fw = fwv[sidx];
    for (int h=h0; h<hend; h++){
        float acc = 0.f;
        #pragma unroll
        for (int c=0;c<CF;c++){
            float m  = s[c]*inv;
            float m2 = q[c]*inv;
            float var = fmaf(-m, m, m2);
            var = fmaxf(var, 1e-6f);
            acc += sqrtf(var);
        }
        float res = acc * 0.125f;
        float val = powf(res, 0.8f);
        size_t oi = ((size_t)b*HH + h)*WW + col;
        fused[oi] += fw * val;
        if (h+1 < hend){
            int ro = reflect_i(h - P);
            int ri = reflect_i(h + 1 + P);
            size_t bo = (((size_t)b*rows_p + (ro-rs_p))*WW + col)*CF;
            size_t bi = (((size_t)b*rows_p + (ri-rs_p))*WW + col)*CF;
            float4 a0 = *(const float4*)(hm +bi);
            float4 a1 = *(const float4*)(hm +bi+4);
            float4 c0 = *(const float4*)(hm2+bi);
            float4 c1 = *(const float4*)(hm2+bi+4);
            ADDLO(s,a0); ADDHI(s,a1); ADDLO(q,c0); ADDHI(q,c1);
            a0 = *(const float4*)(hm +bo);
            a1 = *(const float4*)(hm +bo+4);
            c0 = *(const float4*)(hm2+bo);
            c1 = *(const float4*)(hm2+bo+4);
            SUBLO(s,a0); SUBHI(s,a1); SUBLO(q,c0); SUBHI(q,c1);
        }
    }
}

// ---------------------------------------------------------------------------
// Exact quantile machinery, 3-level radix (8/8/16 bits) with LDS-privatized
// histograms at the contended levels. Values >= 0 -> float bits are
// order-preserving. Ranks for N=2^21: q25 between 524287/524288 (w=0.75),
// q75 between 1572863/1572864 (w=0.25).
// ---------------------------------------------------------------------------
__global__ void k_h8(const float* __restrict__ fused, const float* __restrict__ fb,
                     unsigned* __restrict__ hist8)
{
    __shared__ unsigned lh[256];
    lh[threadIdx.x] = 0;
    __syncthreads();
    float fbv = fb[0];
    int i = blockIdx.x*256 + threadIdx.x;
    int stride = gridDim.x*256;
    for (; i < NPIX; i += stride){
        float v = fmaxf(fused[i] + fbv, 0.f);
        atomicAdd(&lh[__float_as_uint(v) >> 24], 1u);
    }
    __syncthreads();
    if (lh[threadIdx.x]) atomicAdd(&hist8[threadIdx.x], lh[threadIdx.x]);
}

__global__ void k_scan8(const unsigned* __restrict__ hist8,
                        int* __restrict__ cand8, int* __restrict__ rank8)
{
    if (threadIdx.x == 0){
        const unsigned RK[4] = {524287u, 524288u, 1572863u, 1572864u};
        unsigned cum = 0; int qi = 0;
        for (int b = 0; b < 256 && qi < 4; b++){
            unsigned cnt = hist8[b];
            while (qi < 4 && RK[qi] < cum + cnt){
                cand8[qi] = b; rank8[qi] = (int)(RK[qi] - cum); qi++;
            }
            cum += cnt;
        }
    }
}

__global__ void k_h8b(const float* __restrict__ fused, const float* __restrict__ fb,
                      const int* __restrict__ cand8, unsigned* __restrict__ hist8b)
{
    __shared__ unsigned lh[1024];
    for (int i = threadIdx.x; i < 1024; i += 256) lh[i] = 0;
    __syncthreads();
    float fbv = fb[0];
    int c0 = cand8[0], c1 = cand8[1], c2 = cand8[2], c3 = cand8[3];
    // dedupe: only histogram first occurrence of each distinct candidate
    bool d1 = (c1 != c0);
    bool d2 = (c2 != c0) && (c2 != c1);
    bool d3 = (c3 != c0) && (c3 != c1) && (c3 != c2);
    int i = blockIdx.x*256 + threadIdx.x;
    int stride = gridDim.x*256;
    for (; i < NPIX; i += stride){
        unsigned u = __float_as_uint(fmaxf(fused[i] + fbv, 0.f));
        int hi = (int)(u >> 24);
        unsigned mid = (u >> 16) & 0xffu;
        if (hi == c0)       atomicAdd(&lh[mid],       1u);
        if (d1 && hi == c1) atomicAdd(&lh[256u+mid],  1u);
        if (d2 && hi == c2) atomicAdd(&lh[512u+mid],  1u);
        if (d3 && hi == c3) atomicAdd(&lh[768u+mid],  1u);
    }
    __syncthreads();
    for (int i = threadIdx.x; i < 1024; i += 256)
        if (lh[i]) atomicAdd(&hist8b[i], lh[i]);
}

__global__ void k_scan8b(const unsigned* __restrict__ hist8b,
                         const int* __restrict__ cand8, const int* __restrict__ rank8,
                         int* __restrict__ cand16, int* __restrict__ rank16)
{
    int qi = threadIdx.x;
    if (qi < 4){
        // use histogram slot of the first duplicate candidate
        int slot = qi;
        for (int j = 0; j < qi; j++) if (cand8[j] == cand8[qi]){ slot = j; break; }
        const unsigned* h = hist8b + slot*256;
        unsigned k = (unsigned)rank8[qi], cum = 0;
        for (int b = 0; b < 256; b++){
            unsigned cnt = h[b];
            if (cnt && k >= cum && k < cum + cnt){
                cand16[qi] = (cand8[qi] << 8) | b;
                rank16[qi] = (int)(k - cum);
            }
            cum += cnt;
        }
    }
}

__global__ void k_h16(const float* __restrict__ fused, const float* __restrict__ fb,
                      const int* __restrict__ cand16, unsigned* __restrict__ histlo)
{
    float fbv = fb[0];
    int c0 = cand16[0], c1 = cand16[1], c2 = cand16[2], c3 = cand16[3];
    bool d1 = (c1 != c0);
    bool d2 = (c2 != c0) && (c2 != c1);
    bool d3 = (c3 != c0) && (c3 != c1) && (c3 != c2);
    int i = blockIdx.x*256 + threadIdx.x;
    int stride = gridDim.x*256;
    for (; i < NPIX; i += stride){
        unsigned u = __float_as_uint(fmaxf(fused[i] + fbv, 0.f));
        int hi = (int)(u >> 16);
        unsigned lo = u & 0xffffu;
        if (hi == c0)       atomicAdd(&histlo[lo],           1u);
        if (d1 && hi == c1) atomicAdd(&histlo[65536u + lo],  1u);
        if (d2 && hi == c2) atomicAdd(&histlo[131072u + lo], 1u);
        if (d3 && hi == c3) atomicAdd(&histlo[196608u + lo], 1u);
    }
}

__global__ void k_scan16(const unsigned* __restrict__ histlo,
                         const int* __restrict__ cand16, const int* __restrict__ rank16,
                         float* __restrict__ ostat)
{
    int qi = blockIdx.x;
    int slot = qi;
    for (int j = 0; j < qi; j++) if (cand16[j] == cand16[qi]){ slot = j; break; }
    const unsigned* hist = histlo + (size_t)slot*65536;
    __shared__ unsigned csum[256];
    __shared__ unsigned cbase[256];
    int t = threadIdx.x;
    unsigned s = 0;
    for (int i = 0; i < 256; i++) s += hist[t*256 + i];
    csum[t] = s;
    __syncthreads();
    if (t == 0){ unsigned run = 0; for (int i = 0; i < 256; i++){ cbase[i] = run; run += csum[i]; } }
    __syncthreads();
    unsigned k = (unsigned)rank16[qi];
    unsigned cum = cbase[t];
    for (int i = 0; i < 256; i++){
        unsigned cnt = hist[t*256 + i];
        if (cnt && k >= cum && k < cum + cnt)
            ostat[qi] = __uint_as_float(((unsigned)cand16[qi] << 16) | (unsigned)(t*256 + i));
        cum += cnt;
    }
}

// ---------------------------------------------------------------------------
// Global per-(b,c) std of x, ddof=1, via double partial sums (deterministic).
// ---------------------------------------------------------------------------
__global__ void k_gstd_part(const float* __restrict__ x, double* __restrict__ part)
{
    int bid = blockIdx.x;
    int plane = bid >> 3, chunk = bid & 7;
    const float4* p4 = (const float4*)(x + (size_t)plane*HW + (size_t)chunk*32768);
    int t = threadIdx.x;
    double s=0.0, s2=0.0;
    for (int k=0;k<32;k++){
        float4 v = p4[k*256 + t];
        s  += (double)v.x + (double)v.y + (double)v.z + (double)v.w;
        s2 += (double)v.x*v.x + (double)v.y*v.y + (double)v.z*v.z + (double)v.w*v.w;
    }
    __shared__ double rs[256], rq[256];
    rs[t]=s; rq[t]=s2; __syncthreads();
    for (int off=128; off>0; off>>=1){
        if (t<off){ rs[t]+=rs[t+off]; rq[t]+=rq[t+off]; }
        __syncthreads();
    }
    if (t==0){ part[bid*2]=rs[0]; part[bid*2+1]=rq[0]; }
}

__global__ void k_gstd_final(const double* __restrict__ part, float* __restrict__ gstd)
{
    int t = threadIdx.x;
    if (t < 32){
        double s=0.0, s2=0.0;
        for (int j=0;j<8;j++){ s += part[(t*8+j)*2]; s2 += part[(t*8+j)*2+1]; }
        const double N = 262144.0;
        double var = (s2 - s*s/N) / (N - 1.0);
        gstd[t] = (float)sqrt(var < 0.0 ? 0.0 : var);
    }
}

__global__ void k_finalize(const float* __restrict__ ostat, const float* __restrict__ gstd,
                           const float* __restrict__ cwin, float* __restrict__ lov, float* __restrict__ hiv)
{
    int t = threadIdx.x;
    if (t < 32){
        float q25 = ostat[0] + 0.75f*(ostat[1]-ostat[0]);
        float q75 = ostat[2] + 0.25f*(ostat[3]-ostat[2]);
        float iqr = q75 - q25;
        float lo_b = q25 - 0.5f*iqr, hi_b = q75 + 0.5f*iqr;
        int c = t & 3;
        float m = fmaxf(fmaxf(cwin[0],cwin[1]), fmaxf(cwin[2],cwin[3]));
        float e0 = expf(cwin[0]-m), e1 = expf(cwin[1]-m), e2 = expf(cwin[2]-m), e3 = expf(cwin[3]-m);
        float smc = expf(cwin[c]-m) / (e0+e1+e2+e3);
        float g  = gstd[t];
        float gf = fminf(fmaxf(g*5.f, 0.5f), 2.f);
        float cf = fminf(fmaxf(smc*g*2.f, 0.8f), 1.2f);
        lov[t] = lo_b*gf*cf;
        hiv[t] = hi_b*gf*cf;
    }
}

__global__ void k_mask(const float* __restrict__ fused_in, const float* __restrict__ fb,
                       const float* __restrict__ lov, const float* __restrict__ hiv,
                       float* __restrict__ outp)
{
    int i = blockIdx.x*256 + threadIdx.x;
    float F = fmaxf(fused_in[i] + fb[0], 0.f);
    int b = i >> 18;
    float o = 0.f;
    #pragma unroll
    for (int c=0;c<4;c++){
        float lo = lov[b*4+c], hi = hiv[b*4+c];
        float n = (F - lo) / (hi - lo);
        n = fminf(fmaxf(n, 0.f), 1.f);
        o += 1.f/(1.f + expf(3.f - 6.f*n));
    }
    outp[i] = 0.25f * o;
}

// ---------------------------------------------------------------------------
extern "C" void kernel_launch(void* const* d_in, const int* in_sizes, int n_in,
                              void* d_out, int out_size, void* d_ws, size_t ws_size,
                              hipStream_t stream)
{
    const float* x  = (const float*)d_in[0];
    const float* w1 = (const float*)d_in[1];
    const float* b1 = (const float*)d_in[2];
    const float* w2 = (const float*)d_in[3];
    const float* b2 = (const float*)d_in[4];
    const float* w3 = (const float*)d_in[5];
    const float* b3 = (const float*)d_in[6];
    const float* fw = (const float*)d_in[7];
    const float* fb = (const float*)d_in[8];
    const float* cw = (const float*)d_in[9];
    float* out = (float*)d_out;
    char* ws = (char*)d_ws;

    size_t off = 0;
    auto take = [&](size_t bytes)->size_t{ size_t o = off; off += (bytes + 255) & ~(size_t)255; return o; };
    size_t o_f      = take((size_t)NB*CF*HW*4);
    size_t o_h8     = take(256*4);
    size_t o_h8b    = take(1024*4);
    size_t o_histlo = take((size_t)4*65536*4);
    size_t o_c8     = take(4*4);
    size_t o_r8     = take(4*4);
    size_t o_c16    = take(4*4);
    size_t o_r16    = take(4*4);
    size_t o_os     = take(4*4);
    size_t o_part   = take(512*8);
    size_t o_gs     = take(32*4);
    size_t o_lo     = take(32*4);
    size_t o_hi     = take(32*4);
    size_t fixed_end = off;

    size_t szA_pb = (size_t)C2*HW*4, szB_pb = (size_t)C3*HW*4;
    auto hmbytes = [&](int band)->size_t{ return (size_t)NB*(band+48)*WW*CF*4; };
    bool fullconv = false;
    int band = 16;
    if (ws_size >= fixed_end + szA_pb*NB + szB_pb*NB + 2*hmbytes(512) + 4096){
        fullconv = true; band = 512;
    } else {
        const int cand[6] = {512,256,128,64,32,16};
        for (int i=0;i<6;i++){
            if (ws_size >= fixed_end + szA_pb + szB_pb + 2*hmbytes(cand[i]) + 4096){ band = cand[i]; break; }
        }
    }
    size_t o_A   = take(fullconv ? szA_pb*NB : szA_pb);
    size_t o_B   = take(fullconv ? szB_pb*NB : szB_pb);
    size_t o_hm  = take(hmbytes(band));
    size_t o_hm2 = take(hmbytes(band));

    float*    fbuf   = (float*)(ws + o_f);
    float*    f1     = (float*)(ws + o_A);
    float*    f2     = (float*)(ws + o_B);
    float*    hm     = (float*)(ws + o_hm);
    float*    hm2    = (float*)(ws + o_hm2);
    unsigned* hist8  = (unsigned*)(ws + o_h8);
    unsigned* hist8b = (unsigned*)(ws + o_h8b);
    unsigned* histlo = (unsigned*)(ws + o_histlo);
    int*      c8     = (int*)(ws + o_c8);
    int*      r8     = (int*)(ws + o_r8);
    int*      c16    = (int*)(ws + o_c16);
    int*      r16    = (int*)(ws + o_r16);
    float*    osv    = (float*)(ws + o_os);
    double*   part   = (double*)(ws + o_part);
    float*    gs     = (float*)(ws + o_gs);
    float*    lov    = (float*)(ws + o_lo);
    float*    hiv    = (float*)(ws + o_hi);

    // --- conv stack ---
    if (fullconv){
        k_conv<CIN,C2,true ><<<NB*1024,256,0,stream>>>(x,  w1, b1, f1);
        k_conv<C2, C3,true ><<<NB*512, 256,0,stream>>>(f1, w2, b2, f2);
        k_conv<C3, CF,false><<<NB*256, 256,0,stream>>>(f2, w3, b3, fbuf);
    } else {
        for (int b=0;b<NB;b++){
            k_conv<CIN,C2,true ><<<1024,256,0,stream>>>(x + (size_t)b*CIN*HW, w1, b1, f1);
            k_conv<C2, C3,true ><<<512, 256,0,stream>>>(f1, w2, b2, f2);
            k_conv<C3, CF,false><<<256, 256,0,stream>>>(f2, w3, b3, fbuf + (size_t)b*CF*HW);
        }
    }

    // --- global stds (independent of conv chain) ---
    k_gstd_part<<<256,256,0,stream>>>(x, part);
    k_gstd_final<<<1,256,0,stream>>>(part, gs);

    // --- multi-scale std maps, accumulated into d_out as fused sum ---
    hipMemsetAsync(out, 0, (size_t)NPIX*4, stream);
    for (int s=0;s<3;s++){
        int wsz = (s==0) ? 11 : (s==1 ? 25 : 49);
        int P = wsz/2;
        for (int r0=0; r0<HH; r0+=band){
            int r1  = (r0+band < HH) ? r0+band : HH;
            int rsp = (r0-P > 0) ? r0-P : 0;
            int rep = (r1+P < HH) ? r1+P : HH;
            int rows_p = rep - rsp;
            int nch = (r1 - r0 + 15)/16;
            if (wsz==11){
                k_hpass<11><<<NB*rows_p,256,0,stream>>>(fbuf, hm, hm2, rsp, rows_p);
                k_vpass<11><<<16*nch,256,0,stream>>>(hm, hm2, out, fw, s, r0, r1, rsp, rows_p, nch);
            } else if (wsz==25){
                k_hpass<25><<<NB*rows_p,256,0,stream>>>(fbuf, hm, hm2, rsp, rows_p);
                k_vpass<25><<<16*nch,256,0,stream>>>(hm, hm2, out, fw, s, r0, r1, rsp, rows_p, nch);
            } else {
                k_hpass<49><<<NB*rows_p,256,0,stream>>>(fbuf, hm, hm2, rsp, rows_p);
                k_vpass<49><<<16*nch,256,0,stream>>>(hm, hm2, out, fw, s, r0, r1, rsp, rows_p, nch);
            }
        }
    }

    // --- exact quantiles (3-level radix: 8 LDS / 8 LDS / 16 global) ---
    hipMemsetAsync(hist8,  0, 256*4,  stream);
    hipMemsetAsync(hist8b, 0, 1024*4, stream);
    hipMemsetAsync(histlo, 0, (size_t)4*65536*4, stream);
    k_h8    <<<2048,256,0,stream>>>(out, fb, hist8);
    k_scan8 <<<1,64,0,stream>>>(hist8, c8, r8);
    k_h8b   <<<2048,256,0,stream>>>(out, fb, c8, hist8b);
    k_scan8b<<<1,64,0,stream>>>(hist8b, c8, r8, c16, r16);
    k_h16   <<<2048,256,0,stream>>>(out, fb, c16, histlo);
    k_scan16<<<4,256,0,stream>>>(histlo, c16, r16, osv);

    // --- thresholds + mask (in-place on d_out) ---
    k_finalize<<<1,64,0,stream>>>(osv, gs, cw, lov, hiv);
    k_mask<<<NPIX/256,256,0,stream>>>(out, fb, lov, hiv, out);
}

// Round 3
// 1021.601 us; speedup vs baseline: 10.4887x; 1.4516x over previous
//
#include <hip/hip_runtime.h>
#include <cmath>

#define HH 512
#define WW 512
#define NB 8
#define CIN 4
#define C2 32
#define C3 16
#define CF 8
#define HW (HH*WW)      /* 262144 */
#define NPIX (NB*HW)    /* 2097152 */

__device__ __forceinline__ float lrelu_f(float v){ return v < 0.f ? 0.2f*v : v; }
__device__ __forceinline__ int reflect_i(int i){ int r = i < 0 ? -i : i; return r >= HH ? 2*HH - 2 - r : r; }

// ---------------------------------------------------------------------------
// Conv 3x3 (zero pad=1, cross-correlation, OIHW weights). Thread = 4 adjacent
// pixels x 8 output channels. Weights in LDS (uniform -> broadcast reads).
// Handles any number of batches via grid size (b decoded from blockIdx).
// ---------------------------------------------------------------------------
template<int Ci, int Co, bool LRELU>
__global__ __launch_bounds__(256) void k_conv(const float* __restrict__ in,
                                              const float* __restrict__ wgt,
                                              const float* __restrict__ bias,
                                              float* __restrict__ outp)
{
    constexpr int NG = Co/8;
    __shared__ float wl[Co*Ci*9];
    __shared__ float bl[Co];
    for (int i = threadIdx.x; i < Co*Ci*9; i += 256) wl[i] = wgt[i];
    if (threadIdx.x < Co) bl[threadIdx.x] = bias[threadIdx.x];
    __syncthreads();

    int t   = blockIdx.x*256 + threadIdx.x;
    int pix = t & 65535;
    int r   = t >> 16;
    int cg  = r % NG;
    int b   = r / NG;
    int h   = pix >> 7;
    int w0  = (pix & 127) << 2;
    int co0 = cg*8;
    const float* inb = in + (size_t)b*Ci*HW;

    float acc[8][4];
    #pragma unroll
    for (int j=0;j<8;j++){
        float bv = bl[co0+j];
        #pragma unroll
        for (int p=0;p<4;p++) acc[j][p] = bv;
    }

    #pragma unroll 1
    for (int ci=0; ci<Ci; ci++){
        float v[3][6];
        const float* inc = inb + (size_t)ci*HW;
        #pragma unroll
        for (int dy=0;dy<3;dy++){
            int hh = h + dy - 1;
            int hc = hh < 0 ? 0 : (hh > HH-1 ? HH-1 : hh);
            bool hok = (unsigned)hh < (unsigned)HH;
            #pragma unroll
            for (int dx=0;dx<6;dx++){
                int wx = w0 + dx - 1;
                int wc = wx < 0 ? 0 : (wx > WW-1 ? WW-1 : wx);
                float val = inc[hc*WW + wc];
                v[dy][dx] = (hok && (unsigned)wx < (unsigned)WW) ? val : 0.f;
            }
        }
        #pragma unroll
        for (int j=0;j<8;j++){
            const float* wr = &wl[((co0+j)*Ci + ci)*9];
            #pragma unroll
            for (int dy=0;dy<3;dy++){
                #pragma unroll
                for (int dx=0;dx<3;dx++){
                    float wv = wr[dy*3+dx];
                    #pragma unroll
                    for (int p=0;p<4;p++)
                        acc[j][p] = fmaf(v[dy][dx+p], wv, acc[j][p]);
                }
            }
        }
    }

    float* ob = outp + (size_t)b*Co*HW;
    #pragma unroll
    for (int j=0;j<8;j++){
        float4 o;
        o.x = LRELU ? lrelu_f(acc[j][0]) : acc[j][0];
        o.y = LRELU ? lrelu_f(acc[j][1]) : acc[j][1];
        o.z = LRELU ? lrelu_f(acc[j][2]) : acc[j][2];
        o.w = LRELU ? lrelu_f(acc[j][3]) : acc[j][3];
        *(float4*)(ob + (size_t)(co0+j)*HW + h*WW + w0) = o;
    }
}

// ---------------------------------------------------------------------------
// Vertical box pass: per (plane, 256-col strip, 64-row chunk) thread walks a
// column with a register sliding window. Pure streaming, no LDS.
// Outputs per-column window sums of f and f^2 in NCHW layout.
// ---------------------------------------------------------------------------
template<int WS>
__global__ __launch_bounds__(256) void k_vbox(const float* __restrict__ f,
                                              float* __restrict__ vs,
                                              float* __restrict__ vq)
{
    constexpr int P = WS/2;
    constexpr int CH = 64;
    int bid   = blockIdx.x;
    int wb    = bid & 1;
    int hc    = (bid >> 1) & 7;          // HH/CH = 8
    int plane = bid >> 4;
    int w     = wb*256 + threadIdx.x;
    int h0    = hc*CH;
    const float* base = f  + (size_t)plane*HW + w;
    float*       os   = vs + (size_t)plane*HW + w;
    float*       oq   = vq + (size_t)plane*HW + w;

    float s = 0.f, q = 0.f;
    #pragma unroll
    for (int dy = -P; dy <= P; dy++){
        float v = base[(size_t)reflect_i(h0+dy)*WW];
        s += v; q = fmaf(v, v, q);
    }
    #pragma unroll 4
    for (int h = h0; h < h0+CH; h++){
        os[(size_t)h*WW] = s;
        oq[(size_t)h*WW] = q;
        float e = base[(size_t)reflect_i(h+1+P)*WW];
        float l = base[(size_t)reflect_i(h-P)*WW];
        s += e - l;
        q = fmaf(e, e, q);
        q = fmaf(-l, l, q);
    }
}

// ---------------------------------------------------------------------------
// Horizontal box pass + variance + sqrt + channel-combine + pow0.8, writing
// the fused accumulation directly. Block = (b, row). Rows of vs/vq staged in
// LDS with a +1-per-16 pad swizzle; thread = (channel, 16-col segment) with a
// register sliding window (indices fold to compile-time ds_read offsets since
// segment base 16g -> padded base 17g).
// ---------------------------------------------------------------------------
__device__ __forceinline__ int swz_i(int j){ return j + (j >> 4); }

template<int WS>
__global__ __launch_bounds__(256) void k_hbox(const float* __restrict__ vs,
                                              const float* __restrict__ vq,
                                              float* __restrict__ fused,
                                              const float* __restrict__ fwv, int sidx)
{
    constexpr int P   = WS/2;
    constexpr int L   = WW + 2*P;
    constexpr int SWL = L + (L >> 4) + 2;
    constexpr float inv = 1.f/((float)WS*(float)WS);
    __shared__ float sv[CF*SWL];
    __shared__ float sq[CF*SWL];

    int bid = blockIdx.x;
    int row = bid & (HH-1);
    int bb  = bid >> 9;
    const float* vsb = vs + ((size_t)bb*CF*HH + row)*WW;
    const float* vqb = vq + ((size_t)bb*CF*HH + row)*WW;

    for (int i = threadIdx.x; i < CF*L; i += 256){
        int c = i / L, j = i - c*L;
        int s = j - P; s = s < 0 ? -s : (s > WW-1 ? 2*WW-2 - s : s);
        sv[c*SWL + swz_i(j)] = vsb[(size_t)c*HW + s];
        sq[c*SWL + swz_i(j)] = vqb[(size_t)c*HW + s];
    }
    __syncthreads();

    int c = threadIdx.x >> 5;
    int g = threadIdx.x & 31;
    const float* pv = sv + c*SWL;
    const float* pq = sq + c*SWL;
    int bofs = 17*g;                       // swz(16g + k) = 17g + k + (k>>4)

    float S = 0.f, Q = 0.f;
    #pragma unroll
    for (int k = 0; k < WS; k++){
        S += pv[bofs + k + (k>>4)];
        Q += pq[bofs + k + (k>>4)];
    }
    float res[16];
    #pragma unroll
    for (int k = 0; k < 16; k++){
        float m  = S*inv;
        float m2 = Q*inv;
        float var = fmaxf(fmaf(-m, m, m2), 1e-6f);
        res[k] = sqrtf(var);
        if (k < 15){
            S += pv[bofs + (k+WS) + ((k+WS)>>4)] - pv[bofs + k + (k>>4)];
            Q += pq[bofs + (k+WS) + ((k+WS)>>4)] - pq[bofs + k + (k>>4)];
        }
    }
    __syncthreads();
    // reuse sv as per-channel sqrt(var) staging
    #pragma unroll
    for (int k = 0; k < 16; k++) sv[c*SWL + bofs + k + (k>>4)] = res[k];
    __syncthreads();

    float fwb = fwv[sidx];
    #pragma unroll
    for (int half = 0; half < 2; half++){
        int col = threadIdx.x + half*256;
        float a = 0.f;
        #pragma unroll
        for (int cc = 0; cc < CF; cc++) a += sv[cc*SWL + swz_i(col)];
        float val = powf(a*0.125f, 0.8f);
        fused[((size_t)bb*HH + row)*WW + col] += fwb*val;
    }
}

// ---------------------------------------------------------------------------
// Exact quantile machinery, 3-level radix (8/8/16 bits), LDS-privatized at
// the contended levels. Ranks for N=2^21: q25 between 524287/524288 (w=.75),
// q75 between 1572863/1572864 (w=.25).
// ---------------------------------------------------------------------------
__global__ void k_h8(const float* __restrict__ fused, const float* __restrict__ fb,
                     unsigned* __restrict__ hist8)
{
    __shared__ unsigned lh[256];
    lh[threadIdx.x] = 0;
    __syncthreads();
    float fbv = fb[0];
    int i = blockIdx.x*256 + threadIdx.x;
    int stride = gridDim.x*256;
    for (; i < NPIX; i += stride){
        float v = fmaxf(fused[i] + fbv, 0.f);
        atomicAdd(&lh[__float_as_uint(v) >> 24], 1u);
    }
    __syncthreads();
    if (lh[threadIdx.x]) atomicAdd(&hist8[threadIdx.x], lh[threadIdx.x]);
}

__global__ void k_scan8(const unsigned* __restrict__ hist8,
                        int* __restrict__ cand8, int* __restrict__ rank8)
{
    if (threadIdx.x == 0){
        const unsigned RK[4] = {524287u, 524288u, 1572863u, 1572864u};
        unsigned cum = 0; int qi = 0;
        for (int b = 0; b < 256 && qi < 4; b++){
            unsigned cnt = hist8[b];
            while (qi < 4 && RK[qi] < cum + cnt){
                cand8[qi] = b; rank8[qi] = (int)(RK[qi] - cum); qi++;
            }
            cum += cnt;
        }
    }
}

__global__ void k_h8b(const float* __restrict__ fused, const float* __restrict__ fb,
                      const int* __restrict__ cand8, unsigned* __restrict__ hist8b)
{
    __shared__ unsigned lh[1024];
    for (int i = threadIdx.x; i < 1024; i += 256) lh[i] = 0;
    __syncthreads();
    float fbv = fb[0];
    int c0 = cand8[0], c1 = cand8[1], c2 = cand8[2], c3 = cand8[3];
    bool d1 = (c1 != c0);
    bool d2 = (c2 != c0) && (c2 != c1);
    bool d3 = (c3 != c0) && (c3 != c1) && (c3 != c2);
    int i = blockIdx.x*256 + threadIdx.x;
    int stride = gridDim.x*256;
    for (; i < NPIX; i += stride){
        unsigned u = __float_as_uint(fmaxf(fused[i] + fbv, 0.f));
        int hi = (int)(u >> 24);
        unsigned mid = (u >> 16) & 0xffu;
        if (hi == c0)       atomicAdd(&lh[mid],       1u);
        if (d1 && hi == c1) atomicAdd(&lh[256u+mid],  1u);
        if (d2 && hi == c2) atomicAdd(&lh[512u+mid],  1u);
        if (d3 && hi == c3) atomicAdd(&lh[768u+mid],  1u);
    }
    __syncthreads();
    for (int i = threadIdx.x; i < 1024; i += 256)
        if (lh[i]) atomicAdd(&hist8b[i], lh[i]);
}

__global__ void k_scan8b(const unsigned* __restrict__ hist8b,
                         const int* __restrict__ cand8, const int* __restrict__ rank8,
                         int* __restrict__ cand16, int* __restrict__ rank16)
{
    int qi = threadIdx.x;
    if (qi < 4){
        int slot = qi;
        for (int j = 0; j < qi; j++) if (cand8[j] == cand8[qi]){ slot = j; break; }
        const unsigned* h = hist8b + slot*256;
        unsigned k = (unsigned)rank8[qi], cum = 0;
        for (int b = 0; b < 256; b++){
            unsigned cnt = h[b];
            if (cnt && k >= cum && k < cum + cnt){
                cand16[qi] = (cand8[qi] << 8) | b;
                rank16[qi] = (int)(k - cum);
            }
            cum += cnt;
        }
    }
}

__global__ void k_h16(const float* __restrict__ fused, const float* __restrict__ fb,
                      const int* __restrict__ cand16, unsigned* __restrict__ histlo)
{
    float fbv = fb[0];
    int c0 = cand16[0], c1 = cand16[1], c2 = cand16[2], c3 = cand16[3];
    bool d1 = (c1 != c0);
    bool d2 = (c2 != c0) && (c2 != c1);
    bool d3 = (c3 != c0) && (c3 != c1) && (c3 != c2);
    int i = blockIdx.x*256 + threadIdx.x;
    int stride = gridDim.x*256;
    for (; i < NPIX; i += stride){
        unsigned u = __float_as_uint(fmaxf(fused[i] + fbv, 0.f));
        int hi = (int)(u >> 16);
        unsigned lo = u & 0xffffu;
        if (hi == c0)       atomicAdd(&histlo[lo],           1u);
        if (d1 && hi == c1) atomicAdd(&histlo[65536u + lo],  1u);
        if (d2 && hi == c2) atomicAdd(&histlo[131072u + lo], 1u);
        if (d3 && hi == c3) atomicAdd(&histlo[196608u + lo], 1u);
    }
}

__global__ void k_scan16(const unsigned* __restrict__ histlo,
                         const int* __restrict__ cand16, const int* __restrict__ rank16,
                         float* __restrict__ ostat)
{
    int qi = blockIdx.x;
    int slot = qi;
    for (int j = 0; j < qi; j++) if (cand16[j] == cand16[qi]){ slot = j; break; }
    const unsigned* hist = histlo + (size_t)slot*65536;
    __shared__ unsigned csum[256];
    __shared__ unsigned cbase[256];
    int t = threadIdx.x;
    unsigned s = 0;
    for (int i = 0; i < 256; i++) s += hist[t*256 + i];
    csum[t] = s;
    __syncthreads();
    if (t == 0){ unsigned run = 0; for (int i = 0; i < 256; i++){ cbase[i] = run; run += csum[i]; } }
    __syncthreads();
    unsigned k = (unsigned)rank16[qi];
    unsigned cum = cbase[t];
    for (int i = 0; i < 256; i++){
        unsigned cnt = hist[t*256 + i];
        if (cnt && k >= cum && k < cum + cnt)
            ostat[qi] = __uint_as_float(((unsigned)cand16[qi] << 16) | (unsigned)(t*256 + i));
        cum += cnt;
    }
}

// ---------------------------------------------------------------------------
// Global per-(b,c) std of x, ddof=1, via double partial sums (deterministic).
// ---------------------------------------------------------------------------
__global__ void k_gstd_part(const float* __restrict__ x, double* __restrict__ part)
{
    int bid = blockIdx.x;
    int plane = bid >> 3, chunk = bid & 7;
    const float4* p4 = (const float4*)(x + (size_t)plane*HW + (size_t)chunk*32768);
    int t = threadIdx.x;
    double s=0.0, s2=0.0;
    for (int k=0;k<32;k++){
        float4 v = p4[k*256 + t];
        s  += (double)v.x + (double)v.y + (double)v.z + (double)v.w;
        s2 += (double)v.x*v.x + (double)v.y*v.y + (double)v.z*v.z + (double)v.w*v.w;
    }
    __shared__ double rs[256], rq[256];
    rs[t]=s; rq[t]=s2; __syncthreads();
    for (int off=128; off>0; off>>=1){
        if (t<off){ rs[t]+=rs[t+off]; rq[t]+=rq[t+off]; }
        __syncthreads();
    }
    if (t==0){ part[bid*2]=rs[0]; part[bid*2+1]=rq[0]; }
}

__global__ void k_gstd_final(const double* __restrict__ part, float* __restrict__ gstd)
{
    int t = threadIdx.x;
    if (t < 32){
        double s=0.0, s2=0.0;
        for (int j=0;j<8;j++){ s += part[(t*8+j)*2]; s2 += part[(t*8+j)*2+1]; }
        const double N = 262144.0;
        double var = (s2 - s*s/N) / (N - 1.0);
        gstd[t] = (float)sqrt(var < 0.0 ? 0.0 : var);
    }
}

__global__ void k_finalize(const float* __restrict__ ostat, const float* __restrict__ gstd,
                           const float* __restrict__ cwin, float* __restrict__ lov, float* __restrict__ hiv)
{
    int t = threadIdx.x;
    if (t < 32){
        float q25 = ostat[0] + 0.75f*(ostat[1]-ostat[0]);
        float q75 = ostat[2] + 0.25f*(ostat[3]-ostat[2]);
        float iqr = q75 - q25;
        float lo_b = q25 - 0.5f*iqr, hi_b = q75 + 0.5f*iqr;
        int c = t & 3;
        float m = fmaxf(fmaxf(cwin[0],cwin[1]), fmaxf(cwin[2],cwin[3]));
        float e0 = expf(cwin[0]-m), e1 = expf(cwin[1]-m), e2 = expf(cwin[2]-m), e3 = expf(cwin[3]-m);
        float smc = expf(cwin[c]-m) / (e0+e1+e2+e3);
        float g  = gstd[t];
        float gf = fminf(fmaxf(g*5.f, 0.5f), 2.f);
        float cf = fminf(fmaxf(smc*g*2.f, 0.8f), 1.2f);
        lov[t] = lo_b*gf*cf;
        hiv[t] = hi_b*gf*cf;
    }
}

__global__ void k_mask(const float* __restrict__ fused_in, const float* __restrict__ fb,
                       const float* __restrict__ lov, const float* __restrict__ hiv,
                       float* __restrict__ outp)
{
    int i = blockIdx.x*256 + threadIdx.x;
    float F = fmaxf(fused_in[i] + fb[0], 0.f);
    int b = i >> 18;
    float o = 0.f;
    #pragma unroll
    for (int c=0;c<4;c++){
        float lo = lov[b*4+c], hi = hiv[b*4+c];
        float n = (F - lo) / (hi - lo);
        n = fminf(fmaxf(n, 0.f), 1.f);
        o += 1.f/(1.f + expf(3.f - 6.f*n));
    }
    outp[i] = 0.25f * o;
}

// ---------------------------------------------------------------------------
extern "C" void kernel_launch(void* const* d_in, const int* in_sizes, int n_in,
                              void* d_out, int out_size, void* d_ws, size_t ws_size,
                              hipStream_t stream)
{
    const float* x  = (const float*)d_in[0];
    const float* w1 = (const float*)d_in[1];
    const float* b1 = (const float*)d_in[2];
    const float* w2 = (const float*)d_in[3];
    const float* b2 = (const float*)d_in[4];
    const float* w3 = (const float*)d_in[5];
    const float* b3 = (const float*)d_in[6];
    const float* fw = (const float*)d_in[7];
    const float* fb = (const float*)d_in[8];
    const float* cw = (const float*)d_in[9];
    float* out = (float*)d_out;
    char* ws = (char*)d_ws;

    size_t off = 0;
    auto take = [&](size_t bytes)->size_t{ size_t o = off; off += (bytes + 255) & ~(size_t)255; return o; };
    size_t o_f      = take((size_t)NB*CF*HW*4);     // conv3 output, live through all scales
    size_t o_h8     = take(256*4);
    size_t o_h8b    = take(1024*4);
    size_t o_histlo = take((size_t)4*65536*4);
    size_t o_c8     = take(4*4);
    size_t o_r8     = take(4*4);
    size_t o_c16    = take(4*4);
    size_t o_r16    = take(4*4);
    size_t o_os     = take(4*4);
    size_t o_part   = take(512*8);
    size_t o_gs     = take(32*4);
    size_t o_lo     = take(32*4);
    size_t o_hi     = take(32*4);
    size_t fixed_end = off;

    // One reusable region: conv intermediates (f1,f2) first, then (vs,vq).
    size_t avail    = ws_size > fixed_end ? ws_size - fixed_end : 0;
    size_t box_full = (size_t)NB*CF*HW*4*2;          // 128 MB: vs+vq all batches
    size_t box_pb   = (size_t)CF*HW*4*2;             // 16 MB: per-batch
    int NBC = 0; bool boxfull = false;
    const int cands[4] = {8,4,2,1};
    for (int i = 0; i < 4; i++){
        size_t convB = (size_t)cands[i]*(C2+C3)*HW*4;
        size_t need = convB > box_full ? convB : box_full;
        if (need + 1024 <= avail){ NBC = cands[i]; boxfull = true; break; }
    }
    if (!NBC) NBC = 1;  // tight fallback: per-batch box
    size_t convB  = (size_t)NBC*(C2+C3)*HW*4;
    size_t boxB   = boxfull ? box_full : box_pb;
    size_t Rbytes = convB > boxB ? convB : boxB;
    size_t o_R    = take(Rbytes);

    float*    fbuf   = (float*)(ws + o_f);
    float*    f1     = (float*)(ws + o_R);
    float*    f2     = f1 + (size_t)NBC*C2*HW;
    int       nbBox  = boxfull ? NB : 1;
    float*    vsb    = (float*)(ws + o_R);
    float*    vqb    = vsb + (size_t)nbBox*CF*HW;
    unsigned* hist8  = (unsigned*)(ws + o_h8);
    unsigned* hist8b = (unsigned*)(ws + o_h8b);
    unsigned* histlo = (unsigned*)(ws + o_histlo);
    int*      c8     = (int*)(ws + o_c8);
    int*      r8     = (int*)(ws + o_r8);
    int*      c16    = (int*)(ws + o_c16);
    int*      r16    = (int*)(ws + o_r16);
    float*    osv    = (float*)(ws + o_os);
    double*   part   = (double*)(ws + o_part);
    float*    gs     = (float*)(ws + o_gs);
    float*    lov    = (float*)(ws + o_lo);
    float*    hiv    = (float*)(ws + o_hi);

    // --- conv stack, NBC batches per chunk ---
    for (int ck = 0; ck < NB/NBC; ck++){
        const float* xb = x    + (size_t)ck*NBC*CIN*HW;
        float*       fo = fbuf + (size_t)ck*NBC*CF*HW;
        k_conv<CIN,C2,true ><<<NBC*1024,256,0,stream>>>(xb, w1, b1, f1);
        k_conv<C2, C3,true ><<<NBC*512, 256,0,stream>>>(f1, w2, b2, f2);
        k_conv<C3, CF,false><<<NBC*256, 256,0,stream>>>(f2, w3, b3, fo);
    }

    // --- global stds (independent of conv chain) ---
    k_gstd_part<<<256,256,0,stream>>>(x, part);
    k_gstd_final<<<1,256,0,stream>>>(part, gs);

    // --- multi-scale std maps: V box (streaming) then H box (+fused write) ---
    hipMemsetAsync(out, 0, (size_t)NPIX*4, stream);
    if (boxfull){
        const int vgrid = NB*CF*16, hgrid = NB*512;
        k_vbox<11><<<vgrid,256,0,stream>>>(fbuf, vsb, vqb);
        k_hbox<11><<<hgrid,256,0,stream>>>(vsb, vqb, out, fw, 0);
        k_vbox<25><<<vgrid,256,0,stream>>>(fbuf, vsb, vqb);
        k_hbox<25><<<hgrid,256,0,stream>>>(vsb, vqb, out, fw, 1);
        k_vbox<49><<<vgrid,256,0,stream>>>(fbuf, vsb, vqb);
        k_hbox<49><<<hgrid,256,0,stream>>>(vsb, vqb, out, fw, 2);
    } else {
        const int vgrid = CF*16, hgrid = 512;
        for (int b = 0; b < NB; b++){
            const float* fp = fbuf + (size_t)b*CF*HW;
            float*       op = out  + (size_t)b*HW;
            k_vbox<11><<<vgrid,256,0,stream>>>(fp, vsb, vqb);
            k_hbox<11><<<hgrid,256,0,stream>>>(vsb, vqb, op, fw, 0);
            k_vbox<25><<<vgrid,256,0,stream>>>(fp, vsb, vqb);
            k_hbox<25><<<hgrid,256,0,stream>>>(vsb, vqb, op, fw, 1);
            k_vbox<49><<<vgrid,256,0,stream>>>(fp, vsb, vqb);
            k_hbox<49><<<hgrid,256,0,stream>>>(vsb, vqb, op, fw, 2);
        }
    }

    // --- exact quantiles (3-level radix: 8 LDS / 8 LDS / 16 global) ---
    hipMemsetAsync(hist8,  0, 256*4,  stream);
    hipMemsetAsync(hist8b, 0, 1024*4, stream);
    hipMemsetAsync(histlo, 0, (size_t)4*65536*4, stream);
    k_h8    <<<2048,256,0,stream>>>(out, fb, hist8);
    k_scan8 <<<1,64,0,stream>>>(hist8, c8, r8);
    k_h8b   <<<2048,256,0,stream>>>(out, fb, c8, hist8b);
    k_scan8b<<<1,64,0,stream>>>(hist8b, c8, r8, c16, r16);
    k_h16   <<<2048,256,0,stream>>>(out, fb, c16, histlo);
    k_scan16<<<4,256,0,stream>>>(histlo, c16, r16, osv);

    // --- thresholds + mask (in-place on d_out) ---
    k_finalize<<<1,64,0,stream>>>(osv, gs, cw, lov, hiv);
    k_mask<<<NPIX/256,256,0,stream>>>(out, fb, lov, hiv, out);
}